// Round 1
// 127.341 us; speedup vs baseline: 1.0160x; 1.0160x over previous
//
#include <hip/hip_runtime.h>
#include <math.h>

#define NTHREADS 1024
#define NWAVES 16
#define KSEL 100
#define NBINS 2048
#define CAP 1024
#define SCORE_TH 0.1f
#define NMS_TH 0.1f
#define BELONG_TH 0.6f

typedef unsigned long long ull;

// Pack (value, index) so that u64 max == (max value, min index on ties).
__device__ __forceinline__ ull make_key(float f, unsigned gidx) {
    unsigned u = __float_as_uint(f);
    u = (u & 0x80000000u) ? ~u : (u | 0x80000000u);
    return (((ull)u) << 32) | (ull)(0xFFFFFFFFu - gidx);
}
__device__ __forceinline__ float key_val(ull k) {
    unsigned u = (unsigned)(k >> 32);
    u = (u & 0x80000000u) ? (u ^ 0x80000000u) : ~u;
    return __uint_as_float(u);
}
__device__ __forceinline__ unsigned key_idx(ull k) {
    return 0xFFFFFFFFu - (unsigned)(k & 0xFFFFFFFFu);
}
__device__ __forceinline__ float sigmoidf(float x) {
    return 1.0f / (1.0f + expf(-x));
}
// Monotone map p -> bin; used identically in histogram and compaction passes.
__device__ __forceinline__ int binof(float p) {
    int b = (int)(p * (float)NBINS);
    b = b < 0 ? 0 : (b > NBINS - 1 ? NBINS - 1 : b);
    return b;
}

struct SharedMem {
    union {
        unsigned hist[NBINS];   // phase A
        ull cand[CAP];          // phase B (hist dead by then)
        ull part[NWAVES];       // fallback only (cand dead by then)
    } u;
    int bstar;
    int scnt;
    int wsum[NWAVES];
    float prob[KSEL];
    int   sidx[KSEL];
    alignas(16) float box[KSEL][4];
    float data16[KSEL][16];
    float area[KSEL];
    float belong[KSEL];
    ull nmsrow[KSEL][2];
    unsigned char keep[KSEL];
    unsigned char valid[KSEL];
    unsigned char nk[KSEL];
    int argm;
    int anyvk;
};

template <int NPT, bool IS_BEZIER, bool HAS_PARENT>
__device__ void filter_impl(SharedMem* sm,
                            const float* __restrict__ logits,
                            const float* __restrict__ raw,
                            const float* __restrict__ parent_raw,
                            const float* __restrict__ tsizes,
                            float* __restrict__ out_data,
                            float* __restrict__ out_scores,
                            float* __restrict__ out_keep,
                            int img, int N, int PN, int ef) {
    const int tid = threadIdx.x;
    const int lane = tid & 63;
    const int wv = tid >> 6;
    const float* lg = logits + (size_t)img * N;
    const float4* lg4 = (const float4*)lg;

    // ---- init LDS ----
#pragma unroll
    for (int i = tid; i < NBINS; i += NTHREADS) sm->u.hist[i] = 0;
    if (tid == 0) sm->scnt = 0;
    __syncthreads();

    // ---- pass A: load + sigmoid + histogram; RETAIN sigmoid values in
    //      registers so pass B never touches memory again ----
    float q[NPT];
#pragma unroll
    for (int v = 0; v < NPT / 4; ++v) {
        float4 x = lg4[v * NTHREADS + tid];
        q[4 * v + 0] = sigmoidf(x.x);
        q[4 * v + 1] = sigmoidf(x.y);
        q[4 * v + 2] = sigmoidf(x.z);
        q[4 * v + 3] = sigmoidf(x.w);
        atomicAdd(&sm->u.hist[binof(q[4 * v + 0])], 1u);
        atomicAdd(&sm->u.hist[binof(q[4 * v + 1])], 1u);
        atomicAdd(&sm->u.hist[binof(q[4 * v + 2])], 1u);
        atomicAdd(&sm->u.hist[binof(q[4 * v + 3])], 1u);
    }
    __syncthreads();

    // ---- find threshold bin b*: largest b with count(bin >= b) >= KSEL ----
    // thread t owns 2 consecutive bins in DESCENDING order
    int c0 = (int)sm->u.hist[NBINS - 1 - 2 * tid];
    int c1 = (int)sm->u.hist[NBINS - 2 - 2 * tid];
    int s = c0 + c1;
    int vv = s;  // inclusive scan within wave
#pragma unroll
    for (int off = 1; off < 64; off <<= 1) {
        int o = __shfl_up(vv, off, 64);
        if (lane >= off) vv += o;
    }
    if (lane == 63) sm->wsum[wv] = vv;
    __syncthreads();
    int base = 0;
#pragma unroll
    for (int u2 = 0; u2 < NWAVES; ++u2) base += (u2 < wv) ? sm->wsum[u2] : 0;
    int run = base + vv - s;  // count in all strictly-higher bins
    if (run < KSEL && run + c0 >= KSEL) sm->bstar = NBINS - 1 - 2 * tid;
    int run2 = run + c0;
    if (run2 < KSEL && run2 + c1 >= KSEL) sm->bstar = NBINS - 2 - 2 * tid;
    __syncthreads();
    const int bstar = sm->bstar;

    // ---- pass B: compact from retained registers (no reload, no recompute) ----
#pragma unroll
    for (int v = 0; v < NPT / 4; ++v) {
#pragma unroll
        for (int j = 0; j < 4; ++j) {
            float qq = q[4 * v + j];
            if (binof(qq) >= bstar) {
                int pos = atomicAdd(&sm->scnt, 1);
                unsigned gidx = (unsigned)(v * (NTHREADS * 4) + tid * 4 + j);
                if (pos < CAP) sm->u.cand[pos] = make_key(qq, gidx);
            }
        }
    }
    __syncthreads();
    const int cnt = sm->scnt;

    if (cnt <= CAP) {
        // ---- exact rank scatter: rank = #keys strictly greater (keys unique) ----
        for (int t = tid; t < cnt; t += NTHREADS) {
            ull mk = sm->u.cand[t];
            int rank = 0;
            for (int u2 = 0; u2 < cnt; ++u2) rank += (sm->u.cand[u2] > mk) ? 1 : 0;
            if (rank < KSEL) {
                sm->prob[rank] = key_val(mk);
                sm->sidx[rank] = (int)key_idx(mk);
            }
        }
        __syncthreads();
    } else {
        // ---- fallback (degenerate distributions only): threshold descent —
        //      iteration k picks max key strictly < prev; uses retained regs ----
        ull prev = ~0ULL;
        for (int k = 0; k < KSEL; ++k) {
            ull best = 0;
#pragma unroll
            for (int v = 0; v < NPT / 4; ++v) {
#pragma unroll
                for (int j = 0; j < 4; ++j) {
                    ull kk = make_key(q[4 * v + j],
                                      (unsigned)(v * (NTHREADS * 4) + tid * 4 + j));
                    if (kk < prev && kk > best) best = kk;
                }
            }
#pragma unroll
            for (int off = 32; off > 0; off >>= 1) {
                ull o = __shfl_down(best, off, 64);
                if (o > best) best = o;
            }
            if (lane == 0) sm->u.part[wv] = best;
            __syncthreads();
            ull w = sm->u.part[0];
#pragma unroll
            for (int q2 = 1; q2 < NWAVES; ++q2)
                if (sm->u.part[q2] > w) w = sm->u.part[q2];
            if (tid == 0) {
                sm->prob[k] = key_val(w);
                sm->sidx[k] = (int)key_idx(w);
            }
            prev = w;
            __syncthreads();  // part[] reuse next iteration
        }
    }

    const float Himg = tsizes[img * 2 + 0];
    const float Wimg = tsizes[img * 2 + 1];

    // ---- per-selected-box decode (threads 0..99) ----
    if (tid < KSEL) {
        const int k = tid;
        const int si = sm->sidx[k];
        const float val = sm->prob[k];
        const bool any = sm->prob[0] > SCORE_TH;  // sorted desc => any == keep[0]
        bool keep = any ? (val > SCORE_TH) : (k == 0);

        float bx1, by1, bx2, by2;
        if (IS_BEZIER) {
            const float4* r4 = (const float4*)(raw + ((size_t)img * N + si) * 16);
            float c16[16];
#pragma unroll
            for (int v = 0; v < 4; ++v) {
                float4 x = r4[v];
                c16[4 * v + 0] = x.x * Himg;  // tile((h,w),8): even -> h
                c16[4 * v + 1] = x.y * Wimg;  // odd -> w
                c16[4 * v + 2] = x.z * Himg;
                c16[4 * v + 3] = x.w * Wimg;
            }
            float mn0 = INFINITY, mn1 = INFINITY, mx0 = -INFINITY, mx1 = -INFINITY;
            const float step = 1.0f / 9.0f;
#pragma unroll
            for (int sNum = 0; sNum < 10; ++sNum) {
                float t = (float)sNum * step;
                float ti = 1.0f - t;
                float b0 = ti * ti * ti;
                float b1 = 3.0f * t * ti * ti;
                float b2 = 3.0f * t * t * ti;
                float b3 = t * t * t;
#pragma unroll
                for (int cu = 0; cu < 2; ++cu) {
                    const float* cc = c16 + cu * 8;
                    float p0 = b0 * cc[0] + b1 * cc[2] + b2 * cc[4] + b3 * cc[6];
                    float p1 = b0 * cc[1] + b1 * cc[3] + b2 * cc[5] + b3 * cc[7];
                    mn0 = fminf(mn0, p0); mx0 = fmaxf(mx0, p0);
                    mn1 = fminf(mn1, p1); mx1 = fmaxf(mx1, p1);
                }
            }
            bx1 = mn0; by1 = mn1; bx2 = mx0; by2 = mx1;
#pragma unroll
            for (int mm = 0; mm < 16; ++mm) sm->data16[k][mm] = c16[mm];
        } else {
            float4 r = *(const float4*)(raw + ((size_t)img * N + si) * 4);
            float cx = r.x, cy = r.y, w = r.z, h = r.w;
            bx1 = (cx - 0.5f * w) * Wimg;
            by1 = (cy - 0.5f * h) * Himg;
            bx2 = (cx + 0.5f * w) * Wimg;
            by2 = (cy + 0.5f * h) * Himg;
            if (!HAS_PARENT) {  // block level: clip to [0, (W,H)]
                bx1 = fminf(fmaxf(bx1, 0.0f), Wimg);
                by1 = fminf(fmaxf(by1, 0.0f), Himg);
                bx2 = fminf(fmaxf(bx2, 0.0f), Wimg);
                by2 = fminf(fmaxf(by2, 0.0f), Himg);
            }
        }
        sm->box[k][0] = bx1; sm->box[k][1] = by1;
        sm->box[k][2] = bx2; sm->box[k][3] = by2;
        sm->area[k] = (bx2 - bx1) * (by2 - by1);
        sm->keep[k] = keep ? 1 : 0;

        if (HAS_PARENT) {
            int pi = si / ef;
            float4 pr = *(const float4*)(parent_raw + ((size_t)img * PN + pi) * 4);
            float px1 = (pr.x - 0.5f * pr.z) * Wimg;
            float py1 = (pr.y - 0.5f * pr.w) * Himg;
            float px2 = (pr.x + 0.5f * pr.z) * Wimg;
            float py2 = (pr.y + 0.5f * pr.w) * Himg;
            float ix1 = fmaxf(bx1, px1), iy1 = fmaxf(by1, py1);
            float ix2 = fminf(bx2, px2), iy2 = fminf(by2, py2);
            float inter = fmaxf(ix2 - ix1, 0.0f) * fmaxf(iy2 - iy1, 0.0f);
            float carea = (bx2 - bx1) * (by2 - by1);
            float belong = inter / (carea + 1e-6f);
            sm->belong[k] = belong;
            sm->valid[k] = (belong > BELONG_TH) ? 1 : 0;
        }
    }
    __syncthreads();

    // ---- parent validity combine (wave 0) ----
    if (HAS_PARENT) {
        if (tid < 64) {
            ull k0 = make_key(sm->keep[tid] ? sm->belong[tid] : -INFINITY, (unsigned)tid);
            bool p0 = sm->valid[tid] && sm->keep[tid];
            ull k1 = 0;
            bool p1 = false;
            if (tid < KSEL - 64) {
                k1 = make_key(sm->keep[tid + 64] ? sm->belong[tid + 64] : -INFINITY,
                              (unsigned)(tid + 64));
                p1 = sm->valid[tid + 64] && sm->keep[tid + 64];
            }
            ull m = k0 > k1 ? k0 : k1;
#pragma unroll
            for (int off = 32; off > 0; off >>= 1) {
                ull o = __shfl_xor(m, off, 64);
                if (o > m) m = o;
            }
            ull bal = __ballot(p0 || p1);
            if (lane == 0) {
                sm->argm = (int)key_idx(m);   // first max (smallest k on ties)
                sm->anyvk = (bal != 0ULL) ? 1 : 0;
            }
        }
        __syncthreads();
        if (tid < KSEL) {
            bool valid = sm->anyvk ? (sm->valid[tid] != 0) : (tid == sm->argm);
            sm->nk[tid] = (sm->keep[tid] && valid) ? 1 : 0;
        }
    } else {
        if (tid < KSEL) sm->nk[tid] = sm->keep[tid];
    }
    __syncthreads();

    // ---- NMS phase 1: build 100x128 suppression bit-matrix in parallel.
    //      row i bit j = (iou(i,j) > TH) && (j > i). All 16 waves participate. ----
    {
        float4 b0 = *(const float4*)sm->box[lane];
        float a0 = sm->area[lane];
        float4 b1 = make_float4(0.f, 0.f, 0.f, 0.f);
        float a1 = 0.f;
        if (lane < KSEL - 64) {
            b1 = *(const float4*)sm->box[lane + 64];
            a1 = sm->area[lane + 64];
        }
        for (int i = wv; i < KSEL; i += NWAVES) {
            float rx1, ry1, rx2, ry2, ra;
            if (i < 64) {
                rx1 = __shfl(b0.x, i, 64); ry1 = __shfl(b0.y, i, 64);
                rx2 = __shfl(b0.z, i, 64); ry2 = __shfl(b0.w, i, 64);
                ra  = __shfl(a0, i, 64);
            } else {
                rx1 = __shfl(b1.x, i - 64, 64); ry1 = __shfl(b1.y, i - 64, 64);
                rx2 = __shfl(b1.z, i - 64, 64); ry2 = __shfl(b1.w, i - 64, 64);
                ra  = __shfl(a1, i - 64, 64);
            }
            // slot 0: j = lane
            float ix1 = fmaxf(rx1, b0.x), iy1 = fmaxf(ry1, b0.y);
            float ix2 = fminf(rx2, b0.z), iy2 = fminf(ry2, b0.w);
            float in0 = fmaxf(ix2 - ix1, 0.0f) * fmaxf(iy2 - iy1, 0.0f);
            float iou0 = in0 / (ra + a0 - in0);
            bool sup0 = (lane > i) && (iou0 > NMS_TH);  // NaN>th == false
            // slot 1: j = lane + 64
            float jx1 = fmaxf(rx1, b1.x), jy1 = fmaxf(ry1, b1.y);
            float jx2 = fminf(rx2, b1.z), jy2 = fminf(ry2, b1.w);
            float in1 = fmaxf(jx2 - jx1, 0.0f) * fmaxf(jy2 - jy1, 0.0f);
            float iou1 = in1 / (ra + a1 - in1);
            bool sup1 = (lane < KSEL - 64) && ((lane + 64) > i) && (iou1 > NMS_TH);
            ull w0 = __ballot(sup0);
            ull w1 = __ballot(sup1);
            if (lane == 0) { sm->nmsrow[i][0] = w0; sm->nmsrow[i][1] = w1; }
        }
    }
    __syncthreads();

    // ---- NMS phase 2: sequential sweep, skipping suppressed rows via ctz.
    //      Iterations == #survivors (uniform control flow; masks replicated). ----
    if (tid < 64) {
        const int l = lane;
        ull r0lo = sm->nmsrow[l][0], r0hi = sm->nmsrow[l][1];
        ull r1hi = 0;
        if (l < KSEL - 64) r1hi = sm->nmsrow[l + 64][1];
        ull keepLo = __ballot(sm->nk[l] != 0);
        ull keepHi = __ballot((l < KSEL - 64) && (sm->nk[l + 64] != 0));
        ull remLo = keepLo, remHi = keepHi;
        while (remLo | remHi) {
            if (remLo) {
                int i = __builtin_ctzll(remLo);
                ull slo = __shfl(r0lo, i, 64);
                ull shi = __shfl(r0hi, i, 64);
                keepLo &= ~slo;
                keepHi &= ~shi;
                ull gt = (i >= 63) ? 0ULL : (~0ULL << (i + 1));
                remLo = keepLo & gt;
                remHi = keepHi;
            } else {
                int i = __builtin_ctzll(remHi);  // row i+64 suppresses only hi bits
                ull shi = __shfl(r1hi, i, 64);
                keepHi &= ~shi;
                ull gt = (i >= 63) ? 0ULL : (~0ULL << (i + 1));
                remHi = keepHi & gt;
                remLo = 0;
            }
        }
        sm->nk[l] = (unsigned char)((keepLo >> l) & 1ULL);
        if (l < KSEL - 64) sm->nk[l + 64] = (unsigned char)((keepHi >> l) & 1ULL);
    }
    __syncthreads();

    // ---- outputs ----
    if (tid < KSEL) {
        const int k = tid;
        const bool nk = sm->nk[k] != 0;
        out_scores[(size_t)img * KSEL + k] = nk ? sm->prob[k] : 0.0f;
        out_keep[(size_t)img * KSEL + k] = nk ? 1.0f : 0.0f;
        if (IS_BEZIER) {
#pragma unroll
            for (int mm = 0; mm < 16; ++mm)
                out_data[((size_t)img * KSEL + k) * 16 + mm] = nk ? sm->data16[k][mm] : 0.0f;
        } else {
#pragma unroll
            for (int mm = 0; mm < 4; ++mm)
                out_data[((size_t)img * KSEL + k) * 4 + mm] = nk ? sm->box[k][mm] : 0.0f;
        }
    }
}

__global__ __launch_bounds__(NTHREADS) void postprocess_kernel(
    const float* __restrict__ blk_logits, const float* __restrict__ lin_logits,
    const float* __restrict__ chr_logits, const float* __restrict__ blk_raw,
    const float* __restrict__ lin_raw, const float* __restrict__ chr_raw,
    const float* __restrict__ tsizes, float* __restrict__ out) {
    __shared__ SharedMem sm;
    const int b = blockIdx.x;
    const int level = b >> 6;  // 64 images per level
    const int img = b & 63;

    // output layout (B=64, K=100): blk(data,sc,kp), lin(data,sc,kp), chr(data16,sc,kp)
    float* blk_data = out + 0;
    float* blk_sc   = out + 25600;
    float* blk_kp   = out + 32000;
    float* lin_data = out + 38400;
    float* lin_sc   = out + 64000;
    float* lin_kp   = out + 70400;
    float* chr_data = out + 76800;
    float* chr_sc   = out + 179200;
    float* chr_kp   = out + 185600;

    if (level == 0) {
        filter_impl<4, false, false>(&sm, blk_logits, blk_raw, nullptr, tsizes,
                                     blk_data, blk_sc, blk_kp, img, 4096, 0, 1);
    } else if (level == 1) {
        filter_impl<16, false, true>(&sm, lin_logits, lin_raw, blk_raw, tsizes,
                                     lin_data, lin_sc, lin_kp, img, 16384, 4096, 4);
    } else {
        filter_impl<16, true, true>(&sm, chr_logits, chr_raw, lin_raw, tsizes,
                                    chr_data, chr_sc, chr_kp, img, 16384, 16384, 1);
    }
}

extern "C" void kernel_launch(void* const* d_in, const int* in_sizes, int n_in,
                              void* d_out, int out_size, void* d_ws, size_t ws_size,
                              hipStream_t stream) {
    (void)in_sizes; (void)n_in; (void)d_ws; (void)ws_size; (void)out_size;
    const float* blk_logits = (const float*)d_in[0];
    const float* lin_logits = (const float*)d_in[1];
    const float* chr_logits = (const float*)d_in[2];
    const float* blk_raw = (const float*)d_in[3];
    const float* lin_raw = (const float*)d_in[4];
    const float* chr_raw = (const float*)d_in[5];
    const float* tsz = (const float*)d_in[6];
    float* out = (float*)d_out;

    hipLaunchKernelGGL(postprocess_kernel, dim3(192), dim3(NTHREADS), 0, stream,
                       blk_logits, lin_logits, chr_logits, blk_raw, lin_raw,
                       chr_raw, tsz, out);
}